// Round 1
// baseline (359.567 us; speedup 1.0000x reference)
//
#include <hip/hip_runtime.h>

// SharedAdditiveKAN: y = spline(x) @ mix^T + bias
// x: [65536, 512] fp32; bases/slopes: [512, 16] fp32; mix: [512, 512] fp32; bias: [512]
//
// R3 change: BARRIER-FREE K-loop. R2 was latency-bound (MfmaUtil 14%, VALU 20%,
// HBM 28% -- all idle): 32 full vmcnt(0)+lgkmcnt(0) barrier drains per block
// serialized the 8-wave block behind the B-staging L2 round trip every kt.
// Fix: B (mix, 512 KB bf16, L2-resident) is pre-swizzled by prep into MFMA
// fragment-linear order and loaded straight to registers (coalesced 1KB/wave
// global_load_dwordx4). A fragments are computed in-register from direct x
// loads (spline duplicated 2x across the n-halves -- cheap VALU). LDS keeps
// only the spline table; the ONLY __syncthreads is after the table load.
//
// GEMM: BM=128 x BN=512, 512 thr = 8 waves as 4m x 2n; wave tile 32x256:
// 2 fm x 16 fn frags, acc[2][16] (128 VGPRs), mfma_f32_16x16x32_bf16.

#define DIMK 512
#define DIMN 512

typedef unsigned short u16;
typedef unsigned int u32;
typedef __attribute__((ext_vector_type(8))) __bf16 bf16x8;
typedef __attribute__((ext_vector_type(4))) float f32x4;

__device__ __forceinline__ u32 bf16rne(float f) {
    u32 u = __float_as_uint(f);
    return (u + 0x7fffu + ((u >> 16) & 1u)) >> 16;  // round-to-nearest-even
}

// Prep: mix fp32 [O=512][D=512] -> bf16 in fragment-linear layout.
// Fragment element f = (g*16 + kt)*64 + lane (16 B each) holds
// mix[g*16 + (lane&15)][kt*32 + (lane>>4)*8 .. +8], i.e. exactly the
// mfma_16x16x32 B-operand for fragment group g at k-step kt.
__global__ void prep_kernel(const float* __restrict__ mix,
                            u16* __restrict__ mixb) {
    int t = blockIdx.x * 256 + threadIdx.x;  // 32768 threads, 8 elems each
    int lane = t & 63;
    int gk = t >> 6;
    int kt = gk & 15;
    int g = gk >> 4;
    int n = g * 16 + (lane & 15);
    int d = kt * 32 + (lane >> 4) * 8;
    const float4* src = reinterpret_cast<const float4*>(mix + (size_t)n * DIMK + d);
    float4 a = src[0];
    float4 b = src[1];
    ushort4 lo, hi;
    lo.x = (u16)bf16rne(a.x); lo.y = (u16)bf16rne(a.y);
    lo.z = (u16)bf16rne(a.z); lo.w = (u16)bf16rne(a.w);
    hi.x = (u16)bf16rne(b.x); hi.y = (u16)bf16rne(b.y);
    hi.z = (u16)bf16rne(b.z); hi.w = (u16)bf16rne(b.w);
    ushort4* dst = reinterpret_cast<ushort4*>(mixb + (size_t)t * 8);
    dst[0] = lo;
    dst[1] = hi;
}

// 8 splines (one A-fragment's worth) computed fully in registers.
// Table gather: per 16-lane quad-group all lanes share the dim, idx spread
// over 16 consecutive (stride-17-padded) words => ~2-way banked (free).
__device__ __forceinline__ bf16x8 spline8(float4 a, float4 b,
                                          const u32* tab, int dbase) {
    float xs[8] = {a.x, a.y, a.z, a.w, b.x, b.y, b.z, b.w};
    bf16x8 r;
#pragma unroll
    for (int j = 0; j < 8; j++) {
        // EXACT reference index math (fp32): xn = clip((x+1)*0.5, 0, 0.999999)
        float xn = fminf(fmaxf((xs[j] + 1.0f) * 0.5f, 0.0f), 0.999999f);
        float tt = xn * 16.0f;
        int idx = (int)tt;  // 0..15 guaranteed
        u32 p = tab[(dbase + j) * 17 + idx];
        float base = __uint_as_float(p << 16);
        float slope = __uint_as_float(p & 0xffff0000u);
        float sp = fmaf(slope, tt - (float)idx, base);
        r[j] = (__bf16)sp;  // RNE, v_cvt_pk_bf16_f32-able
    }
    return r;
}

__global__ __launch_bounds__(512, 2) void kan_kernel(
    const float* __restrict__ x, const float* __restrict__ bases,
    const float* __restrict__ slopes, const u16* __restrict__ mixb,
    const float* __restrict__ bias, float* __restrict__ y) {
    // Spline table: (base,slope) bf16-pair packed in u32, stride 17 words/dim.
    __shared__ u32 s_tab[DIMK * 17];  // 34816 B -- only LDS in the kernel

    const int tid = threadIdx.x;
    const int lane = tid & 63;
    const int wid = tid >> 6;      // 0..7
    const int quad = lane >> 4;    // 0..3
    const int l15 = lane & 15;
    const int wave_m = wid >> 1;   // 0..3 : 32-row slice
    const int wave_n = wid & 1;    // 0..1 : 256-col half
    const int m0 = blockIdx.x * 128;

    // ---- one-time: spline table -> LDS (coalesced fp32 reads) ----
#pragma unroll
    for (int k = 0; k < 16; k++) {
        int i = tid + k * 512;  // 0..8191 over [D=512][G=16]
        u32 p = bf16rne(bases[i]) | (bf16rne(slopes[i]) << 16);
        s_tab[(i >> 4) * 17 + (i & 15)] = p;
    }

    // x pointers: lane reads rows (m0 + wave_m*32 + fm*16 + l15),
    // cols kt*32 + quad*8 .. +8 (two float4s).
    const float4* xp0 = reinterpret_cast<const float4*>(
                            x + (size_t)(m0 + wave_m * 32 + l15) * DIMK) +
                        quad * 2;
    const float4* xp1 = xp0 + 16 * (DIMK / 4);  // +16 rows

    // B: fragment-linear, g = wave_n*16 + fn; element (g*16+kt)*64 + lane.
    const bf16x8* bp = reinterpret_cast<const bf16x8*>(mixb) +
                       (size_t)wave_n * 16384 + lane;

    f32x4 acc[2][16];
#pragma unroll
    for (int i = 0; i < 2; i++)
#pragma unroll
        for (int j = 0; j < 16; j++) acc[i][j] = (f32x4){0.f, 0.f, 0.f, 0.f};

    // preload x for kt=0
    float4 xa0 = xp0[0], xa1 = xp0[1];
    float4 xb0 = xp1[0], xb1 = xp1[1];

    __syncthreads();  // s_tab ready -- the only barrier in the kernel

    for (int kt = 0; kt < 16; ++kt) {
        const int kto = kt * 64;

        // x prefetch for kt+1 (longest-latency stream, issue first).
        // kt==15 wraps to 0: valid memory, result unused.
        const int ktn = ((kt + 1) & 15) * 8;
        float4 n0 = xp0[ktn], n1 = xp0[ktn + 1];
        float4 n2 = xp1[ktn], n3 = xp1[ktn + 1];

        // B batch 1 (fn 0..7): L2-hot loads, latency hidden by spline VALU.
        bf16x8 bf[8];
#pragma unroll
        for (int fn = 0; fn < 8; fn++) bf[fn] = bp[fn * 1024 + kto];

        // A fragments: 16 splines in registers (shared by both n-halves'
        // waves => 2x duplicated chip-wide, ~free on the VALU pipe).
        const int dbase = kt * 32 + quad * 8;
        bf16x8 af0 = spline8(xa0, xa1, s_tab, dbase);
        bf16x8 af1 = spline8(xb0, xb1, s_tab, dbase);

        // B batch 2 issued before batch-1 MFMAs: hides under them.
        bf16x8 bg[8];
#pragma unroll
        for (int fn = 0; fn < 8; fn++) bg[fn] = bp[(8 + fn) * 1024 + kto];

#pragma unroll
        for (int fn = 0; fn < 8; fn++) {
            acc[0][fn] = __builtin_amdgcn_mfma_f32_16x16x32_bf16(
                af0, bf[fn], acc[0][fn], 0, 0, 0);
            acc[1][fn] = __builtin_amdgcn_mfma_f32_16x16x32_bf16(
                af1, bf[fn], acc[1][fn], 0, 0, 0);
        }
#pragma unroll
        for (int fn = 0; fn < 8; fn++) {
            acc[0][8 + fn] = __builtin_amdgcn_mfma_f32_16x16x32_bf16(
                af0, bg[fn], acc[0][8 + fn], 0, 0, 0);
            acc[1][8 + fn] = __builtin_amdgcn_mfma_f32_16x16x32_bf16(
                af1, bg[fn], acc[1][8 + fn], 0, 0, 0);
        }

        xa0 = n0; xa1 = n1; xb0 = n2; xb1 = n3;
    }

    // ---- epilogue: C/D layout col=lane&15, row=quad*4+j ----
#pragma unroll
    for (int fn = 0; fn < 16; fn++) {
        int o = wave_n * 256 + fn * 16 + l15;
        float bv = bias[o];
#pragma unroll
        for (int fm = 0; fm < 2; fm++) {
            int row = m0 + wave_m * 32 + fm * 16 + quad * 4;
            float* yp = y + (size_t)row * DIMN + o;
#pragma unroll
            for (int j = 0; j < 4; j++)
                yp[(size_t)j * DIMN] = acc[fm][fn][j] + bv;
        }
    }
}

extern "C" void kernel_launch(void* const* d_in, const int* in_sizes, int n_in,
                              void* d_out, int out_size, void* d_ws, size_t ws_size,
                              hipStream_t stream) {
    const float* x = (const float*)d_in[0];
    const float* bases = (const float*)d_in[1];
    const float* slopes = (const float*)d_in[2];
    const float* mix = (const float*)d_in[3];
    const float* bias = (const float*)d_in[4];
    float* y = (float*)d_out;

    u16* mixb = (u16*)d_ws;  // 512 KB bf16 mix, fragment-linear

    hipLaunchKernelGGL(prep_kernel, dim3(128), dim3(256), 0, stream, mix, mixb);
    hipLaunchKernelGGL(kan_kernel, dim3(512), dim3(512), 0, stream,
                       x, bases, slopes, mixb, bias, y);
}

// Round 2
// 260.797 us; speedup vs baseline: 1.3787x; 1.3787x over previous
//
#include <hip/hip_runtime.h>

// SharedAdditiveKAN: y = spline(x) @ mix^T + bias
// x: [65536, 512] fp32; bases/slopes: [512, 16] fp32; mix: [512, 512] fp32; bias: [512]
//
// R4: back to the proven R2 structure (95.8us: LDS-staged A via spline+ds_write,
// B via global_load_lds w=16, XOR-swizzled tiles), but DOUBLE-BUFFERED with one
// barrier per kt (T3 minimum 2-phase recipe). R2 was serialization-bound: single
// buffer forced {stage -> full vmcnt(0)+lgkm drain -> compute -> barrier} with
// zero cross-kt overlap (all pipes <30% busy). R3 (per-wave reg loads, no LDS)
// regressed 2x: scattered 16Bx64-lane VMEM + 4x B duplication choked the memory
// path -- reverted.
// Key realization: R2 was ALREADY 1 block/CU (96 VGPR + 128 AGPR acc = 224/wave
// -> 2 waves/SIMD), so doubling LDS to 116.7KB costs no occupancy.
// Now stage(t+1) (spline VALU + ds_write A, glds B) overlaps compute(t) MFMAs;
// x prefetched at iteration top for max in-flight time before the barrier drain.
//
// GEMM: BM=128 x BN=512 (x read exactly once), BK=32, 512 thr = 8 waves (2m x 4n),
// mfma_f32_16x16x32_bf16, 4x8 frags/wave, acc in AGPRs.

#define DIMK 512
#define DIMN 512

typedef unsigned short u16;
typedef unsigned int u32;
typedef __attribute__((ext_vector_type(8))) __bf16 bf16x8;
typedef __attribute__((ext_vector_type(4))) float f32x4;

__device__ __forceinline__ u32 bf16rne(float f) {
    u32 u = __float_as_uint(f);
    return (u + 0x7fffu + ((u >> 16) & 1u)) >> 16;  // round-to-nearest-even
}

// Prep: convert mix fp32 -> bf16 (ushort bits) into ws, row-major.
__global__ void prep_kernel(const float* __restrict__ mix,
                            u16* __restrict__ mixb) {
    int t = blockIdx.x * 256 + threadIdx.x;             // 65536 threads
    float4 v = reinterpret_cast<const float4*>(mix)[t]; // 4 mix elems each
    ushort4 o;
    o.x = (u16)bf16rne(v.x);
    o.y = (u16)bf16rne(v.y);
    o.z = (u16)bf16rne(v.z);
    o.w = (u16)bf16rne(v.w);
    reinterpret_cast<ushort4*>(mixb)[t] = o;
}

__global__ __launch_bounds__(512, 2) void kan_kernel(
    const float* __restrict__ x, const float* __restrict__ bases,
    const float* __restrict__ slopes, const u16* __restrict__ mixb,
    const float* __restrict__ bias, float* __restrict__ y) {
    // Spline table: (base,slope) packed bf16 pair, stride 17 words per dim so
    // the 16-value idx gather spreads over banks (~2-way, ~free).
    __shared__ u32 s_tab[DIMK * 17];                 // 34816 B
    // Double-buffered XOR-swizzled tiles: row r, k-chunk c (16B) at
    // chunk (r<<2)|(c^((r>>1)&3)).
    __shared__ __align__(16) u16 sA[2][128 * 32];    // 16 KB
    __shared__ __align__(16) u16 sB[2][512 * 32];    // 64 KB
    // total 116736 B -> 1 block/CU (R2 was already 1 block/CU via registers)

    const int tid = threadIdx.x;
    const int lane = tid & 63;
    const int wid = tid >> 6;       // 0..7
    const int quad = lane >> 4;     // 0..3
    const int l15 = lane & 15;
    const int wave_m = wid >> 2;    // 0..1
    const int wave_n = wid & 3;     // 0..3
    const int m0 = blockIdx.x * 128;

    // ---- one-time: load spline table into LDS (coalesced fp32 reads) ----
#pragma unroll
    for (int k = 0; k < 16; k++) {
        int i = tid + k * 512;      // 0..8191 over [D=512][G=16]
        u32 p = bf16rne(bases[i]) | (bf16rne(slopes[i]) << 16);
        s_tab[(i >> 4) * 17 + (i & 15)] = p;
    }

    // A staging: thread t handles row ar (0..127), k-chunk akg (0..3) = 8 elems
    const int ar = tid >> 2;
    const int akg = tid & 3;
    const int awchunk = (ar << 2) | (akg ^ ((ar >> 1) & 3));
    const float4* xrow =
        reinterpret_cast<const float4*>(x + (size_t)(m0 + ar) * DIMK) + akg * 2;

    f32x4 acc[4][8];
#pragma unroll
    for (int i = 0; i < 4; i++)
#pragma unroll
        for (int j = 0; j < 8; j++) acc[i][j] = (f32x4){0.f, 0.f, 0.f, 0.f};

    // ---- staging helpers (inlined lambdas) ----
    auto stage_a = [&](u16* sAb, float4 a, float4 b, int kt) {
        float xs[8] = {a.x, a.y, a.z, a.w, b.x, b.y, b.z, b.w};
        const int dbase = kt * 32 + akg * 8;
        u32 h[8];
#pragma unroll
        for (int j = 0; j < 8; j++) {
            // EXACT replication of reference index math (fp32).
            float xn = fminf(fmaxf((xs[j] + 1.0f) * 0.5f, 0.0f), 0.999999f);
            float tt = xn * 16.0f;
            int idx = (int)tt;  // 0..15 guaranteed
            u32 p = s_tab[(dbase + j) * 17 + idx];
            float base = __uint_as_float(p << 16);
            float slope = __uint_as_float(p & 0xffff0000u);
            float sp = fmaf(slope, tt - (float)idx, base);
            h[j] = bf16rne(sp);
        }
        int4 pk = make_int4((int)(h[0] | (h[1] << 16)), (int)(h[2] | (h[3] << 16)),
                            (int)(h[4] | (h[5] << 16)), (int)(h[6] | (h[7] << 16)));
        *reinterpret_cast<int4*>(&sAb[awchunk * 8]) = pk;
    };
    auto stage_b = [&](u16* sBb, int kt) {
#pragma unroll
        for (int i = 0; i < 4; i++) {
            int grp = wid * 4 + i;                // 16-row group, 0..31
            int n = grp * 16 + (lane >> 2);
            int c = (lane & 3) ^ ((n >> 1) & 3);  // global k-chunk this lane fetches
            const u16* gsrc = mixb + (size_t)n * DIMK + kt * 32 + c * 8;
            __builtin_amdgcn_global_load_lds(
                (const __attribute__((address_space(1))) void*)gsrc,
                (__attribute__((address_space(3))) void*)(&sBb[grp * 512]),
                16, 0, 0);
        }
    };

    // ---- prologue ----
    float4 p0 = xrow[0], p1 = xrow[1];           // x(kt=0)
    __syncthreads();                             // s_tab ready
    stage_a(&sA[0][0], p0, p1, 0);
    stage_b(&sB[0][0], 0);
    float4 xs0a = xrow[8], xs0b = xrow[9];       // x(kt=1) for next stage
    __syncthreads();                             // buf0 staged (full drain, once)

    int cur = 0;
    for (int kt = 0; kt < 16; ++kt) {
        // x prefetch for kt+2, issued first => max in-flight before barrier.
        float4 xna = xs0a, xnb = xs0b;
        if (kt < 14) {
            xna = xrow[(kt + 2) * 8];
            xnb = xrow[(kt + 2) * 8 + 1];
        }

        // stage next kt into the other buffer: spline VALU + ds_write + glds,
        // all overlapping this kt's MFMAs below (separate pipes / counted waits).
        if (kt < 15) {
            stage_a(&sA[cur ^ 1][0], xs0a, xs0b, kt + 1);
            stage_b(&sB[cur ^ 1][0], kt + 1);
        }

        // ---- compute on buf[cur]: 32 MFMAs per wave ----
        const u16* sAc = &sA[cur][0];
        const u16* sBc = &sB[cur][0];
        bf16x8 afrag[4];
#pragma unroll
        for (int fm = 0; fm < 4; fm++) {
            int m_l = wave_m * 64 + fm * 16 + l15;
            int ci = (m_l << 2) | (quad ^ ((m_l >> 1) & 3));
            afrag[fm] = *reinterpret_cast<const bf16x8*>(&sAc[ci * 8]);
        }
#pragma unroll
        for (int fn = 0; fn < 8; fn++) {
            int n_l = wave_n * 128 + fn * 16 + l15;
            int ci = (n_l << 2) | (quad ^ ((n_l >> 1) & 3));
            bf16x8 bfrag = *reinterpret_cast<const bf16x8*>(&sBc[ci * 8]);
#pragma unroll
            for (int fm = 0; fm < 4; fm++)
                acc[fm][fn] = __builtin_amdgcn_mfma_f32_16x16x32_bf16(
                    afrag[fm], bfrag, acc[fm][fn], 0, 0, 0);
        }

        if (kt < 15) __syncthreads();  // next buffer fully staged & visible
        xs0a = xna; xs0b = xnb;
        cur ^= 1;
    }

    // ---- epilogue: C/D layout col=lane&15, row=quad*4+j ----
#pragma unroll
    for (int fn = 0; fn < 8; fn++) {
        int o = wave_n * 128 + fn * 16 + l15;
        float bv = bias[o];
#pragma unroll
        for (int fm = 0; fm < 4; fm++) {
            int row = m0 + wave_m * 64 + fm * 16 + quad * 4;
            float* yp = y + (size_t)row * DIMN + o;
#pragma unroll
            for (int j = 0; j < 4; j++)
                yp[(size_t)j * DIMN] = acc[fm][fn][j] + bv;
        }
    }
}

extern "C" void kernel_launch(void* const* d_in, const int* in_sizes, int n_in,
                              void* d_out, int out_size, void* d_ws, size_t ws_size,
                              hipStream_t stream) {
    const float* x = (const float*)d_in[0];
    const float* bases = (const float*)d_in[1];
    const float* slopes = (const float*)d_in[2];
    const float* mix = (const float*)d_in[3];
    const float* bias = (const float*)d_in[4];
    float* y = (float*)d_out;

    u16* mixb = (u16*)d_ws;  // 512 KB bf16 mix

    hipLaunchKernelGGL(prep_kernel, dim3(256), dim3(256), 0, stream, mix, mixb);
    hipLaunchKernelGGL(kan_kernel, dim3(512), dim3(512), 0, stream,
                       x, bases, slopes, mixb, bias, y);
}